// Round 2
// baseline (349.645 us; speedup 1.0000x reference)
//
#include <hip/hip_runtime.h>

typedef __attribute__((ext_vector_type(8))) short short8;
typedef __attribute__((ext_vector_type(4))) float floatx4;

#define HW 4096
#define CIN 256
#define CK 128
#define COUT 256
#define NB 4
#define BN_EPS 1e-5f
#define SCALE 0.08838834764831843f
// SCALE * log2(e): softmax done in exp2 domain
#define SC2 0.12751744526f

#define MFMA(a, b, c) __builtin_amdgcn_mfma_f32_16x16x32_bf16((a), (b), (c), 0, 0, 0)

__device__ __forceinline__ unsigned short f2bf(float f) {
  union { float f; unsigned u; } v; v.f = f;
  unsigned r = v.u + 0x7fffu + ((v.u >> 16) & 1u);  // RNE
  return (unsigned short)(r >> 16);
}

__device__ __forceinline__ short8 pack8(const float* p) {
  short8 r;
#pragma unroll
  for (int i = 0; i < 8; ++i) r[i] = (short)f2bf(p[i]);
  return r;
}

// ---------------------------------------------------------------------------
// Kernel 1: QKV projections + BN/ReLU epilogue.
// grid (64 p-tiles, 4 batch, 3 proj), block 256.
// Q -> Qb[b][p][c] bf16 ; K -> Kb[b][p][c] bf16 ; V -> Vt[b][c][p] bf16.
// ---------------------------------------------------------------------------
__global__ __launch_bounds__(256) void proj_kernel(
    const float* __restrict__ x_enc, const float* __restrict__ x_dec,
    const float* __restrict__ wq, const float* __restrict__ bq,
    const float* __restrict__ gq, const float* __restrict__ betaq,
    const float* __restrict__ mq, const float* __restrict__ vq,
    const float* __restrict__ wk, const float* __restrict__ bk,
    const float* __restrict__ gk, const float* __restrict__ betak,
    const float* __restrict__ mk, const float* __restrict__ vk,
    const float* __restrict__ wv, const float* __restrict__ bv,
    unsigned short* __restrict__ Qb, unsigned short* __restrict__ Kb,
    unsigned short* __restrict__ Vt)
{
  const int tid = threadIdx.x;
  const int pt = blockIdx.x;  // p-tile (64 positions)
  const int b  = blockIdx.y;
  const int pj = blockIdx.z;  // 0:Q(x_dec) 1:K(x_enc) 2:V(x_enc)

  const float* X = (pj == 0) ? x_dec : x_enc;
  const float* W = (pj == 0) ? wq : (pj == 1 ? wk : wv);

  __shared__ unsigned short xT[64 * 264];  // [p][c], stride 264 (16B-aligned rows)

  {
    const float* Xs = X + (size_t)b * CIN * HW + (size_t)pt * 64;
    const int tr = tid >> 4;
    const int tc = tid & 15;
#pragma unroll
    for (int pass = 0; pass < 16; ++pass) {
      const int c = pass * 16 + tr;
      const float4 v = *(const float4*)(Xs + (size_t)c * HW + tc * 4);
      xT[(tc * 4 + 0) * 264 + c] = f2bf(v.x);
      xT[(tc * 4 + 1) * 264 + c] = f2bf(v.y);
      xT[(tc * 4 + 2) * 264 + c] = f2bf(v.z);
      xT[(tc * 4 + 3) * 264 + c] = f2bf(v.w);
    }
  }
  __syncthreads();

  const int wave = tid >> 6;
  const int lane = tid & 63;
  const int lane16 = lane & 15;
  const int quad = lane >> 4;

  floatx4 acc[2][4];
#pragma unroll
  for (int mt = 0; mt < 2; ++mt)
#pragma unroll
    for (int nf = 0; nf < 4; ++nf) acc[mt][nf] = (floatx4){0.f, 0.f, 0.f, 0.f};

#pragma unroll
  for (int ks = 0; ks < 8; ++ks) {
    short8 af[2];
#pragma unroll
    for (int mt = 0; mt < 2; ++mt) {
      const int o = wave * 32 + mt * 16 + lane16;
      const float* Wr = W + (size_t)o * CIN + ks * 32 + quad * 8;
      float t[8];
      *(float4*)(t) = *(const float4*)(Wr);
      *(float4*)(t + 4) = *(const float4*)(Wr + 4);
      af[mt] = pack8(t);
    }
#pragma unroll
    for (int nf = 0; nf < 4; ++nf) {
      const short8 bf = *(const short8*)&xT[(nf * 16 + lane16) * 264 + ks * 32 + quad * 8];
#pragma unroll
      for (int mt = 0; mt < 2; ++mt) acc[mt][nf] = MFMA(af[mt], bf, acc[mt][nf]);
    }
  }

  if (pj == 2) {
#pragma unroll
    for (int mt = 0; mt < 2; ++mt) {
#pragma unroll
      for (int r = 0; r < 4; ++r) {
        const int c = wave * 32 + mt * 16 + quad * 4 + r;
        const float bias = bv[c];
        unsigned short* dst = Vt + ((size_t)(b * CK + c)) * HW + pt * 64;
#pragma unroll
        for (int nf = 0; nf < 4; ++nf)
          dst[nf * 16 + lane16] = f2bf(acc[mt][nf][r] + bias);
      }
    }
  } else {
    const float* bias  = pj ? bk : bq;
    const float* gamma = pj ? gk : gq;
    const float* beta  = pj ? betak : betaq;
    const float* mean  = pj ? mk : mq;
    const float* var   = pj ? vk : vq;
    unsigned short* Out = pj ? Kb : Qb;
    float sc[2][4], off[2][4];
#pragma unroll
    for (int mt = 0; mt < 2; ++mt)
#pragma unroll
      for (int r = 0; r < 4; ++r) {
        const int o = wave * 32 + mt * 16 + quad * 4 + r;
        const float s = gamma[o] * rsqrtf(var[o] + BN_EPS);
        sc[mt][r] = s;
        off[mt][r] = (bias[o] - mean[o]) * s + beta[o];
      }
#pragma unroll
    for (int nf = 0; nf < 4; ++nf) {
      const size_t prow = ((size_t)b * HW + pt * 64 + nf * 16 + lane16) * CK;
#pragma unroll
      for (int mt = 0; mt < 2; ++mt) {
        ushort4 pk;
        pk.x = f2bf(fmaxf(acc[mt][nf][0] * sc[mt][0] + off[mt][0], 0.f));
        pk.y = f2bf(fmaxf(acc[mt][nf][1] * sc[mt][1] + off[mt][1], 0.f));
        pk.z = f2bf(fmaxf(acc[mt][nf][2] * sc[mt][2] + off[mt][2], 0.f));
        pk.w = f2bf(fmaxf(acc[mt][nf][3] * sc[mt][3] + off[mt][3], 0.f));
        *(ushort4*)(Out + prow + wave * 32 + mt * 16 + quad * 4) = pk;
      }
    }
  }
}

// ---------------------------------------------------------------------------
// Kernel 2a: split-K flash attention, no barriers, K/V frags direct from L2.
// grid 128*NKC blocks (b=blk&3, qt=(blk>>2)&31, kc=blk>>7), block 256 (4 waves).
// Each wave: 32 q rows x (4096/NKC) keys. Writes unnormalized partial O (fp32)
// + per-row (m,l) in exp2 domain.
// ---------------------------------------------------------------------------
template<int NKC>
__global__ __launch_bounds__(256) void attn_split_kernel(
    const unsigned short* __restrict__ Qb, const unsigned short* __restrict__ Kb,
    const unsigned short* __restrict__ Vt, float* __restrict__ Opart,
    float* __restrict__ Ml)
{
  constexpr int ITERS = 64 / NKC;
  const int tid = threadIdx.x;
  const int blk = blockIdx.x;
  const int b  = blk & 3;               // batch -> XCD pair for K/V L2 residency
  const int qt = (blk >> 2) & 31;
  const int kc = blk >> 7;

  const int wave = tid >> 6;
  const int lane = tid & 63;
  const int lane16 = lane & 15;
  const int quad = lane >> 4;

  __shared__ unsigned short Pl[4][32 * 72];  // per-wave P transpose buffer
  unsigned short* Pw = &Pl[wave][0];

  const int q0 = qt * 128 + wave * 32;

  // Q A-frags (A: m=lane16, k=quad*8+j), persistent
  short8 qf[2][4];
  {
    const unsigned short* Qs = Qb + ((size_t)b * HW + q0) * CK;
#pragma unroll
    for (int mt = 0; mt < 2; ++mt)
#pragma unroll
      for (int ks = 0; ks < 4; ++ks)
        qf[mt][ks] = *(const short8*)(Qs + (size_t)(mt * 16 + lane16) * CK + ks * 32 + quad * 8);
  }

  float m_r[2][4], l_r[2][4], alpha[2][4];
  floatx4 O[2][8];
#pragma unroll
  for (int mt = 0; mt < 2; ++mt)
#pragma unroll
    for (int r = 0; r < 4; ++r) { m_r[mt][r] = -1e30f; l_r[mt][r] = 0.f; }
#pragma unroll
  for (int mt = 0; mt < 2; ++mt)
#pragma unroll
    for (int nf = 0; nf < 8; ++nf) O[mt][nf] = (floatx4){0.f, 0.f, 0.f, 0.f};

  const unsigned short* Kbase = Kb + (size_t)b * HW * CK;
  const unsigned short* Vbase = Vt + (size_t)b * CK * HW;

  for (int it = 0; it < ITERS; ++it) {
    const int kp0 = kc * (ITERS * 64) + it * 64;

    // S = Q K^T  (32 q x 64 kp), K B-frags straight from global (L2-hot)
    floatx4 S[2][4];
#pragma unroll
    for (int mt = 0; mt < 2; ++mt)
#pragma unroll
      for (int nf = 0; nf < 4; ++nf) S[mt][nf] = (floatx4){0.f, 0.f, 0.f, 0.f};
    {
      const unsigned short* Kt = Kbase + (size_t)kp0 * CK;
#pragma unroll
      for (int ks = 0; ks < 4; ++ks)
#pragma unroll
        for (int nf = 0; nf < 4; ++nf) {
          const short8 kf = *(const short8*)(Kt + (size_t)(nf * 16 + lane16) * CK + ks * 32 + quad * 8);
          S[0][nf] = MFMA(qf[0][ks], kf, S[0][nf]);
          S[1][nf] = MFMA(qf[1][ks], kf, S[1][nf]);
        }
    }

    // online softmax in exp2 domain (rows live across lane16 within each quad)
#pragma unroll
    for (int mt = 0; mt < 2; ++mt)
#pragma unroll
      for (int r = 0; r < 4; ++r) {
        float t = fmaxf(fmaxf(S[mt][0][r], S[mt][1][r]), fmaxf(S[mt][2][r], S[mt][3][r]));
        t = fmaxf(t, __shfl_xor(t, 1));
        t = fmaxf(t, __shfl_xor(t, 2));
        t = fmaxf(t, __shfl_xor(t, 4));
        t = fmaxf(t, __shfl_xor(t, 8));
        const float m2 = fmaxf(m_r[mt][r], t * SC2);
        const float al = exp2f(m_r[mt][r] - m2);
        m_r[mt][r] = m2;
        alpha[mt][r] = al;
        l_r[mt][r] *= al;
      }

    // P = exp2(S*SC2 - m); write transposed to LDS; accumulate row sums
#pragma unroll
    for (int mt = 0; mt < 2; ++mt)
#pragma unroll
      for (int r = 0; r < 4; ++r) {
        float s = 0.f;
        const float mrow = m_r[mt][r];
#pragma unroll
        for (int nf = 0; nf < 4; ++nf) {
          const float p = exp2f(fmaf(S[mt][nf][r], SC2, -mrow));
          s += p;
          Pw[(mt * 16 + quad * 4 + r) * 72 + nf * 16 + lane16] = f2bf(p);
        }
        s += __shfl_xor(s, 1);
        s += __shfl_xor(s, 2);
        s += __shfl_xor(s, 4);
        s += __shfl_xor(s, 8);
        l_r[mt][r] += s;
      }

    // rescale O
#pragma unroll
    for (int mt = 0; mt < 2; ++mt)
#pragma unroll
      for (int nf = 0; nf < 8; ++nf)
#pragma unroll
        for (int r = 0; r < 4; ++r) O[mt][nf][r] *= alpha[mt][r];

    __threadfence_block();  // drain P ds_writes before cross-lane ds_read

    // O += P V  (V B-frags direct from global Vt[c][p], contiguous in p)
#pragma unroll
    for (int ks = 0; ks < 2; ++ks) {
      const short8 pf0 = *(const short8*)&Pw[(lane16) * 72 + ks * 32 + quad * 8];
      const short8 pf1 = *(const short8*)&Pw[(16 + lane16) * 72 + ks * 32 + quad * 8];
      const unsigned short* Vk = Vbase + kp0 + ks * 32 + quad * 8;
#pragma unroll
      for (int nf = 0; nf < 8; ++nf) {
        const short8 vf = *(const short8*)(Vk + (size_t)(nf * 16 + lane16) * HW);
        O[0][nf] = MFMA(pf0, vf, O[0][nf]);
        O[1][nf] = MFMA(pf1, vf, O[1][nf]);
      }
    }
  }

  // epilogue: unnormalized partial O + (m,l)
  const int chunk = (b * 32 + qt) * NKC + kc;
  float* Op = Opart + (size_t)chunk * (128 * 128);
#pragma unroll
  for (int mt = 0; mt < 2; ++mt)
#pragma unroll
    for (int nf = 0; nf < 8; ++nf)
#pragma unroll
      for (int r = 0; r < 4; ++r)
        Op[(size_t)(wave * 32 + mt * 16 + quad * 4 + r) * 128 + nf * 16 + lane16] = O[mt][nf][r];
  if (lane16 == 0) {
    float* Mlp = Ml + (size_t)chunk * 256;
#pragma unroll
    for (int mt = 0; mt < 2; ++mt)
#pragma unroll
      for (int r = 0; r < 4; ++r) {
        const int ql = wave * 32 + mt * 16 + quad * 4 + r;
        Mlp[ql] = m_r[mt][r];
        Mlp[128 + ql] = l_r[mt][r];
      }
  }
}

// ---------------------------------------------------------------------------
// Kernel 2b: combine NKC partials -> ctx bf16. grid 512 (b, qt, 32-q slice).
// ---------------------------------------------------------------------------
template<int NKC>
__global__ __launch_bounds__(256) void attn_combine_kernel(
    const float* __restrict__ Opart, const float* __restrict__ Ml,
    unsigned short* __restrict__ ctx)
{
  const int tid = threadIdx.x;
  const int blk = blockIdx.x;
  const int b  = blk & 3;
  const int qt = (blk >> 2) & 31;
  const int qs = blk >> 7;
  const int ql = qs * 32 + (tid >> 3);
  const int c0 = (tid & 7) * 16;

  const int chunk0 = (b * 32 + qt) * NKC;
  float m_k[NKC], l_k[NKC], w[NKC];
  float M = -1e30f;
#pragma unroll
  for (int k = 0; k < NKC; ++k) {
    m_k[k] = Ml[(size_t)(chunk0 + k) * 256 + ql];
    l_k[k] = Ml[(size_t)(chunk0 + k) * 256 + 128 + ql];
    M = fmaxf(M, m_k[k]);
  }
  float L = 0.f;
#pragma unroll
  for (int k = 0; k < NKC; ++k) { w[k] = exp2f(m_k[k] - M); L += l_k[k] * w[k]; }
  const float invL = 1.f / L;

  float acc[16];
#pragma unroll
  for (int i = 0; i < 16; ++i) acc[i] = 0.f;
#pragma unroll
  for (int k = 0; k < NKC; ++k) {
    const float* Op = Opart + (size_t)(chunk0 + k) * 16384 + (size_t)ql * 128 + c0;
    const float wk = w[k];
#pragma unroll
    for (int j = 0; j < 4; ++j) {
      const float4 v = *(const float4*)(Op + j * 4);
      acc[j * 4 + 0] += wk * v.x;
      acc[j * 4 + 1] += wk * v.y;
      acc[j * 4 + 2] += wk * v.z;
      acc[j * 4 + 3] += wk * v.w;
    }
  }
  unsigned short* Cs = ctx + ((size_t)b * HW + qt * 128 + ql) * CK + c0;
#pragma unroll
  for (int i = 0; i < 16; ++i) Cs[i] = f2bf(acc[i] * invL);
}

// ---------------------------------------------------------------------------
// Fallback (round-1) attention: in-place, grid 256. Used only if ws too small.
// ---------------------------------------------------------------------------
__global__ __launch_bounds__(256) void attn_kernel(
    const unsigned short* __restrict__ Qb, const unsigned short* __restrict__ Kb,
    const unsigned short* __restrict__ Vt, unsigned short* __restrict__ ctx)
{
  const int tid = threadIdx.x;
  const int b = blockIdx.x & 3;
  const int qt = blockIdx.x >> 2;
  const int wave = tid >> 6;
  const int lane = tid & 63;
  const int lane16 = lane & 15;
  const int quad = lane >> 4;

  __shared__ unsigned short Kl[64 * 136];
  __shared__ unsigned short Vl[128 * 72];
  __shared__ unsigned short Pl[4][16 * 72];

  short8 qf[4];
  {
    const unsigned short* Qs = Qb + ((size_t)b * HW + qt * 64 + wave * 16 + lane16) * CK;
#pragma unroll
    for (int ks = 0; ks < 4; ++ks) qf[ks] = *(const short8*)(Qs + ks * 32 + quad * 8);
  }

  float m_r[4], l_r[4];
  floatx4 O[8];
#pragma unroll
  for (int r = 0; r < 4; ++r) { m_r[r] = -1e30f; l_r[r] = 0.f; }
#pragma unroll
  for (int nf = 0; nf < 8; ++nf) O[nf] = (floatx4){0.f, 0.f, 0.f, 0.f};

  const unsigned short* Ksrc0 = Kb + (size_t)b * HW * CK;
  const unsigned short* Vsrc0 = Vt + (size_t)b * CK * HW;

  for (int kt = 0; kt < 64; ++kt) {
    __syncthreads();
    {
      const unsigned short* Ks = Ksrc0 + (size_t)(kt * 64) * CK;
      const int r = tid >> 4, cc = tid & 15;
#pragma unroll
      for (int pass = 0; pass < 4; ++pass) {
        const int row = pass * 16 + r;
        *(short8*)&Kl[row * 136 + cc * 8] = *(const short8*)(Ks + row * CK + cc * 8);
      }
      const unsigned short* Vs = Vsrc0 + kt * 64;
      const int vr = tid >> 3, vc = tid & 7;
#pragma unroll
      for (int pass = 0; pass < 4; ++pass) {
        const int row = pass * 32 + vr;
        *(short8*)&Vl[row * 72 + vc * 8] = *(const short8*)(Vs + (size_t)row * HW + vc * 8);
      }
    }
    __syncthreads();

    floatx4 S[4];
#pragma unroll
    for (int nf = 0; nf < 4; ++nf) S[nf] = (floatx4){0.f, 0.f, 0.f, 0.f};
#pragma unroll
    for (int ks = 0; ks < 4; ++ks) {
#pragma unroll
      for (int nf = 0; nf < 4; ++nf) {
        const short8 kf = *(const short8*)&Kl[(nf * 16 + lane16) * 136 + ks * 32 + quad * 8];
        S[nf] = MFMA(qf[ks], kf, S[nf]);
      }
    }

    float mnew[4], alpha[4];
#pragma unroll
    for (int r = 0; r < 4; ++r) {
      float t = fmaxf(fmaxf(S[0][r], S[1][r]), fmaxf(S[2][r], S[3][r])) * SCALE;
      t = fmaxf(t, __shfl_xor(t, 1));
      t = fmaxf(t, __shfl_xor(t, 2));
      t = fmaxf(t, __shfl_xor(t, 4));
      t = fmaxf(t, __shfl_xor(t, 8));
      mnew[r] = fmaxf(m_r[r], t);
      alpha[r] = __expf(m_r[r] - mnew[r]);
      m_r[r] = mnew[r];
    }
    float P[4][4];
#pragma unroll
    for (int nf = 0; nf < 4; ++nf)
#pragma unroll
      for (int r = 0; r < 4; ++r) P[nf][r] = __expf(S[nf][r] * SCALE - mnew[r]);
#pragma unroll
    for (int r = 0; r < 4; ++r) {
      float s = (P[0][r] + P[1][r]) + (P[2][r] + P[3][r]);
      s += __shfl_xor(s, 1);
      s += __shfl_xor(s, 2);
      s += __shfl_xor(s, 4);
      s += __shfl_xor(s, 8);
      l_r[r] = l_r[r] * alpha[r] + s;
    }

    unsigned short* Pw = &Pl[wave][0];
#pragma unroll
    for (int nf = 0; nf < 4; ++nf)
#pragma unroll
      for (int r = 0; r < 4; ++r)
        Pw[(quad * 4 + r) * 72 + nf * 16 + lane16] = f2bf(P[nf][r]);

#pragma unroll
    for (int nf = 0; nf < 8; ++nf)
#pragma unroll
      for (int r = 0; r < 4; ++r) O[nf][r] *= alpha[r];

    __threadfence_block();

#pragma unroll
    for (int ks = 0; ks < 2; ++ks) {
      const short8 pf = *(const short8*)&Pw[lane16 * 72 + ks * 32 + quad * 8];
#pragma unroll
      for (int nf = 0; nf < 8; ++nf) {
        const short8 vf = *(const short8*)&Vl[(nf * 16 + lane16) * 72 + ks * 32 + quad * 8];
        O[nf] = MFMA(pf, vf, O[nf]);
      }
    }
  }

  float inv[4];
#pragma unroll
  for (int r = 0; r < 4; ++r) inv[r] = 1.f / l_r[r];
  unsigned short* Cs = ctx + ((size_t)b * HW + qt * 64 + wave * 16) * CK;
#pragma unroll
  for (int nf = 0; nf < 8; ++nf)
#pragma unroll
    for (int r = 0; r < 4; ++r)
      Cs[(size_t)(quad * 4 + r) * CK + nf * 16 + lane16] = f2bf(O[nf][r] * inv[r]);
}

// ---------------------------------------------------------------------------
// Kernel 3: out = Wo @ ctx^T + bo. grid (64 p-tiles, 4 batch), block 256.
// ---------------------------------------------------------------------------
__global__ __launch_bounds__(256) void outproj_kernel(
    const unsigned short* __restrict__ ctx, const float* __restrict__ wo,
    const float* __restrict__ bo, float* __restrict__ out)
{
  const int tid = threadIdx.x;
  const int pt = blockIdx.x;
  const int b  = blockIdx.y;
  const int wave = tid >> 6;
  const int lane = tid & 63;
  const int lane16 = lane & 15;
  const int quad = lane >> 4;

  floatx4 acc[4][4];
#pragma unroll
  for (int mt = 0; mt < 4; ++mt)
#pragma unroll
    for (int nf = 0; nf < 4; ++nf) acc[mt][nf] = (floatx4){0.f, 0.f, 0.f, 0.f};

#pragma unroll
  for (int ks = 0; ks < 4; ++ks) {
    short8 af[4];
#pragma unroll
    for (int mt = 0; mt < 4; ++mt) {
      const int o = wave * 64 + mt * 16 + lane16;
      const float* Wr = wo + (size_t)o * CK + ks * 32 + quad * 8;
      float t[8];
      *(float4*)(t) = *(const float4*)(Wr);
      *(float4*)(t + 4) = *(const float4*)(Wr + 4);
      af[mt] = pack8(t);
    }
#pragma unroll
    for (int nf = 0; nf < 4; ++nf) {
      const short8 bf = *(const short8*)(ctx + ((size_t)b * HW + pt * 64 + nf * 16 + lane16) * CK + ks * 32 + quad * 8);
#pragma unroll
      for (int mt = 0; mt < 4; ++mt) acc[mt][nf] = MFMA(af[mt], bf, acc[mt][nf]);
    }
  }

#pragma unroll
  for (int mt = 0; mt < 4; ++mt) {
#pragma unroll
    for (int r = 0; r < 4; ++r) {
      const int o = wave * 64 + mt * 16 + quad * 4 + r;
      const float bias = bo[o];
      float* dst = out + ((size_t)b * COUT + o) * HW + pt * 64;
#pragma unroll
      for (int nf = 0; nf < 4; ++nf)
        dst[nf * 16 + lane16] = acc[mt][nf][r] + bias;
    }
  }
}

extern "C" void kernel_launch(void* const* d_in, const int* in_sizes, int n_in,
                              void* d_out, int out_size, void* d_ws, size_t ws_size,
                              hipStream_t stream)
{
  (void)in_sizes; (void)n_in; (void)out_size;
  const float* x_enc = (const float*)d_in[0];
  const float* x_dec = (const float*)d_in[1];
  const float* wk    = (const float*)d_in[2];
  const float* bk    = (const float*)d_in[3];
  const float* gk    = (const float*)d_in[4];
  const float* betak = (const float*)d_in[5];
  const float* mk    = (const float*)d_in[6];
  const float* vk    = (const float*)d_in[7];
  const float* wq    = (const float*)d_in[8];
  const float* bq    = (const float*)d_in[9];
  const float* gq    = (const float*)d_in[10];
  const float* betaq = (const float*)d_in[11];
  const float* mq    = (const float*)d_in[12];
  const float* vq    = (const float*)d_in[13];
  const float* wv    = (const float*)d_in[14];
  const float* bv    = (const float*)d_in[15];
  const float* wo    = (const float*)d_in[16];
  const float* bo    = (const float*)d_in[17];
  float* out = (float*)d_out;

  const size_t qkv = (size_t)NB * HW * CK;         // elems per bf16 tensor
  unsigned short* Qb  = (unsigned short*)d_ws;
  unsigned short* Kb  = Qb + qkv;
  unsigned short* Vt  = Kb + qkv;
  unsigned short* ctx = Vt + qkv;
  float* Opart = (float*)(ctx + qkv);              // starts at 16 MB, 16B-aligned
  const size_t bf16_bytes = 4 * qkv * 2;

  proj_kernel<<<dim3(64, 4, 3), 256, 0, stream>>>(
      x_enc, x_dec, wq, bq, gq, betaq, mq, vq,
      wk, bk, gk, betak, mk, vk, wv, bv, Qb, Kb, Vt);

  auto need = [&](int nkc) {
    return bf16_bytes + (size_t)128 * nkc * (16384 + 256) * sizeof(float);
  };
  if (ws_size >= need(8)) {
    float* Ml = Opart + (size_t)128 * 8 * 16384;
    attn_split_kernel<8><<<dim3(1024), 256, 0, stream>>>(Qb, Kb, Vt, Opart, Ml);
    attn_combine_kernel<8><<<dim3(512), 256, 0, stream>>>(Opart, Ml, ctx);
  } else if (ws_size >= need(4)) {
    float* Ml = Opart + (size_t)128 * 4 * 16384;
    attn_split_kernel<4><<<dim3(512), 256, 0, stream>>>(Qb, Kb, Vt, Opart, Ml);
    attn_combine_kernel<4><<<dim3(512), 256, 0, stream>>>(Opart, Ml, ctx);
  } else {
    attn_kernel<<<dim3(256), 256, 0, stream>>>(Qb, Kb, Vt, ctx);
  }

  outproj_kernel<<<dim3(64, 4), 256, 0, stream>>>(ctx, wo, bo, out);
}

// Round 3
// 189.751 us; speedup vs baseline: 1.8427x; 1.8427x over previous
//
#include <hip/hip_runtime.h>

typedef __attribute__((ext_vector_type(8))) short short8;
typedef __attribute__((ext_vector_type(4))) float floatx4;

#define HW 4096
#define CIN 256
#define CK 128
#define COUT 256
#define NB 4
#define BN_EPS 1e-5f
// (1/sqrt(128)) * log2(e), folded into Q at projection time -> P = exp2(S)
#define SC2 0.12751744526f

#define MFMA(a, b, c) __builtin_amdgcn_mfma_f32_16x16x32_bf16((a), (b), (c), 0, 0, 0)

__device__ __forceinline__ unsigned short f2bf(float f) {
  union { float f; unsigned u; } v; v.f = f;
  unsigned r = v.u + 0x7fffu + ((v.u >> 16) & 1u);  // RNE
  return (unsigned short)(r >> 16);
}

__device__ __forceinline__ short8 pack8(const float* p) {
  short8 r;
#pragma unroll
  for (int i = 0; i < 8; ++i) r[i] = (short)f2bf(p[i]);
  return r;
}

// ---------------------------------------------------------------------------
// Kernel 1: QKV projections + BN/ReLU epilogue. grid (64, 4, 3), block 256.
// Two-phase LDS transpose (replaces round-1's 16-way-conflicted scalar path):
//  a1: coalesced float4 global -> xF[c][p] f32  (conflict-free)
//  a2: stride reads (2-way) -> pack -> b128 writes to xT[p][c]
// Q is pre-scaled by SC2. Q/K -> [p][c] bf16, V -> [c][p] bf16.
// ---------------------------------------------------------------------------
__global__ __launch_bounds__(256) void proj_kernel(
    const float* __restrict__ x_enc, const float* __restrict__ x_dec,
    const float* __restrict__ wq, const float* __restrict__ bq,
    const float* __restrict__ gq, const float* __restrict__ betaq,
    const float* __restrict__ mq, const float* __restrict__ vq,
    const float* __restrict__ wk, const float* __restrict__ bk,
    const float* __restrict__ gk, const float* __restrict__ betak,
    const float* __restrict__ mk, const float* __restrict__ vk,
    const float* __restrict__ wv, const float* __restrict__ bv,
    unsigned short* __restrict__ Qb, unsigned short* __restrict__ Kb,
    unsigned short* __restrict__ Vt)
{
  const int tid = threadIdx.x;
  const int pt = blockIdx.x;  // 64-position tile
  const int b  = blockIdx.y;
  const int pj = blockIdx.z;  // 0:Q(x_dec) 1:K(x_enc) 2:V(x_enc)

  const float* X = (pj == 0) ? x_dec : x_enc;
  const float* W = (pj == 0) ? wq : (pj == 1 ? wk : wv);

  __shared__ float xF[64 * 68];             // quarter of c-range, stride 68
  __shared__ unsigned short xT[64 * 264];   // [p][c] bf16, stride 264

  const float* Xs = X + (size_t)b * CIN * HW + (size_t)pt * 64;
#pragma unroll
  for (int qtr = 0; qtr < 4; ++qtr) {
    if (qtr) __syncthreads();
    {
      const int c = tid >> 2;            // 0..63
      const int p0 = (tid & 3) * 16;
      const float* src = Xs + (size_t)(qtr * 64 + c) * HW + p0;
#pragma unroll
      for (int j = 0; j < 4; ++j)
        *(float4*)&xF[c * 68 + p0 + j * 4] = *(const float4*)(src + j * 4);
    }
    __syncthreads();
    {
      const int p = tid & 63;
      const int cb = tid >> 6;           // 0..3
#pragma unroll
      for (int jj = 0; jj < 2; ++jj) {
        const int c0 = (jj * 4 + cb) * 8;  // 0..56 step 8
        float t[8];
#pragma unroll
        for (int u = 0; u < 8; ++u) t[u] = xF[(c0 + u) * 68 + p];
        *(short8*)&xT[p * 264 + qtr * 64 + c0] = pack8(t);
      }
    }
  }
  __syncthreads();

  const int wave = tid >> 6;
  const int lane = tid & 63;
  const int lane16 = lane & 15;
  const int quad = lane >> 4;

  floatx4 acc[2][4];
#pragma unroll
  for (int mt = 0; mt < 2; ++mt)
#pragma unroll
    for (int nf = 0; nf < 4; ++nf) acc[mt][nf] = (floatx4){0.f, 0.f, 0.f, 0.f};

#pragma unroll
  for (int ks = 0; ks < 8; ++ks) {
    short8 af[2];
#pragma unroll
    for (int mt = 0; mt < 2; ++mt) {
      const int o = wave * 32 + mt * 16 + lane16;
      const float* Wr = W + (size_t)o * CIN + ks * 32 + quad * 8;
      float t[8];
      *(float4*)(t) = *(const float4*)(Wr);
      *(float4*)(t + 4) = *(const float4*)(Wr + 4);
      af[mt] = pack8(t);
    }
#pragma unroll
    for (int nf = 0; nf < 4; ++nf) {
      const short8 bf = *(const short8*)&xT[(nf * 16 + lane16) * 264 + ks * 32 + quad * 8];
#pragma unroll
      for (int mt = 0; mt < 2; ++mt) acc[mt][nf] = MFMA(af[mt], bf, acc[mt][nf]);
    }
  }

  if (pj == 2) {
#pragma unroll
    for (int mt = 0; mt < 2; ++mt) {
#pragma unroll
      for (int r = 0; r < 4; ++r) {
        const int c = wave * 32 + mt * 16 + quad * 4 + r;
        const float bias = bv[c];
        unsigned short* dst = Vt + ((size_t)(b * CK + c)) * HW + pt * 64;
#pragma unroll
        for (int nf = 0; nf < 4; ++nf)
          dst[nf * 16 + lane16] = f2bf(acc[mt][nf][r] + bias);
      }
    }
  } else {
    const float* bias  = pj ? bk : bq;
    const float* gamma = pj ? gk : gq;
    const float* beta  = pj ? betak : betaq;
    const float* mean  = pj ? mk : mq;
    const float* var   = pj ? vk : vq;
    const float qs     = pj ? 1.f : SC2;   // fold softmax scale*log2e into Q
    unsigned short* Out = pj ? Kb : Qb;
    float sc[2][4], off[2][4];
#pragma unroll
    for (int mt = 0; mt < 2; ++mt)
#pragma unroll
      for (int r = 0; r < 4; ++r) {
        const int o = wave * 32 + mt * 16 + quad * 4 + r;
        const float s = gamma[o] * rsqrtf(var[o] + BN_EPS) * qs;
        sc[mt][r] = s;
        off[mt][r] = (bias[o] - mean[o]) * s + beta[o] * qs;
      }
#pragma unroll
    for (int nf = 0; nf < 4; ++nf) {
      const size_t prow = ((size_t)b * HW + pt * 64 + nf * 16 + lane16) * CK;
#pragma unroll
      for (int mt = 0; mt < 2; ++mt) {
        ushort4 pk;
        pk.x = f2bf(fmaxf(acc[mt][nf][0] * sc[mt][0] + off[mt][0], 0.f));
        pk.y = f2bf(fmaxf(acc[mt][nf][1] * sc[mt][1] + off[mt][1], 0.f));
        pk.z = f2bf(fmaxf(acc[mt][nf][2] * sc[mt][2] + off[mt][2], 0.f));
        pk.w = f2bf(fmaxf(acc[mt][nf][3] * sc[mt][3] + off[mt][3], 0.f));
        *(ushort4*)(Out + prow + wave * 32 + mt * 16 + quad * 4) = pk;
      }
    }
  }
}

// ---------------------------------------------------------------------------
// Kernel 2a: split-K flash attention, LDS-staged K/V, shuffle-free softmax.
// grid 128*NKC (b=blk&3, qt=(blk>>2)&31, kc=blk>>7), block 256 (4 waves).
// Wave owns 32 q rows. No max-tracking (SC2 pre-folded; exp2 in fp32 safe);
// row-sum l via MFMA against all-ones B-fragment (zero cross-lane ops).
// Writes unnormalized partial O (fp32) + l per row.
// ---------------------------------------------------------------------------
template<int NKC>
__global__ __launch_bounds__(256, 2) void attn_kernel3(
    const unsigned short* __restrict__ Qb, const unsigned short* __restrict__ Kb,
    const unsigned short* __restrict__ Vt, float* __restrict__ Opart,
    float* __restrict__ Ml)
{
  constexpr int ITERS = 64 / NKC;
  const int tid = threadIdx.x;
  const int blk = blockIdx.x;
  const int b  = blk & 3;
  const int qt = (blk >> 2) & 31;
  const int kc = blk >> 7;

  const int wave = tid >> 6;
  const int lane = tid & 63;
  const int lane16 = lane & 15;
  const int quad = lane >> 4;

  __shared__ unsigned short Kl[64 * 136];    // [kp][c], stride 136
  __shared__ unsigned short Vl[128 * 72];    // [c][kp], stride 72
  __shared__ unsigned short Pl[4][32 * 72];  // per-wave [q][kp], stride 72
  unsigned short* Pw = &Pl[wave][0];

  const int q0 = qt * 128 + wave * 32;
  short8 qf[2][4];
  {
    const unsigned short* Qs = Qb + ((size_t)b * HW + q0) * CK;
#pragma unroll
    for (int mt = 0; mt < 2; ++mt)
#pragma unroll
      for (int ks = 0; ks < 4; ++ks)
        qf[mt][ks] = *(const short8*)(Qs + (size_t)(mt * 16 + lane16) * CK + ks * 32 + quad * 8);
  }

  short8 ones;
#pragma unroll
  for (int i = 0; i < 8; ++i) ones[i] = (short)0x3F80;  // bf16 1.0

  floatx4 O[2][8];
  floatx4 Lacc[2];
#pragma unroll
  for (int mt = 0; mt < 2; ++mt) {
    Lacc[mt] = (floatx4){0.f, 0.f, 0.f, 0.f};
#pragma unroll
    for (int nf = 0; nf < 8; ++nf) O[mt][nf] = (floatx4){0.f, 0.f, 0.f, 0.f};
  }

  const unsigned short* Kg0 = Kb + (size_t)b * HW * CK;
  const unsigned short* Vg0 = Vt + (size_t)b * CK * HW;

  // staging assignments (256 threads stage 16KB K + 16KB V per iter)
  const int krow = tid >> 4;           // 0..15
  const int kcol = (tid & 15) * 8;     // shorts
  const int vrow = tid >> 1;           // 0..127 (channel)
  const int vcol = (tid & 1) * 32;     // shorts

  for (int it = 0; it < ITERS; ++it) {
    const int kp0 = kc * (ITERS * 64) + it * 64;
    __syncthreads();
    {
      const unsigned short* Kg = Kg0 + (size_t)kp0 * CK;
      short8 kr[4], vr[4];
#pragma unroll
      for (int i2 = 0; i2 < 4; ++i2)
        kr[i2] = *(const short8*)(Kg + (size_t)(krow + i2 * 16) * CK + kcol);
      const unsigned short* Vg = Vg0 + (size_t)vrow * HW + kp0 + vcol;
#pragma unroll
      for (int i2 = 0; i2 < 4; ++i2)
        vr[i2] = *(const short8*)(Vg + i2 * 8);
#pragma unroll
      for (int i2 = 0; i2 < 4; ++i2)
        *(short8*)&Kl[(krow + i2 * 16) * 136 + kcol] = kr[i2];
#pragma unroll
      for (int i2 = 0; i2 < 4; ++i2)
        *(short8*)&Vl[vrow * 72 + vcol + i2 * 8] = vr[i2];
    }
    __syncthreads();

    // S = Q K^T per 16-col tile, P = exp2(S) immediately (no max needed)
#pragma unroll
    for (int nf = 0; nf < 4; ++nf) {
      floatx4 s0 = (floatx4){0.f, 0.f, 0.f, 0.f};
      floatx4 s1 = (floatx4){0.f, 0.f, 0.f, 0.f};
#pragma unroll
      for (int ks = 0; ks < 4; ++ks) {
        const short8 kf = *(const short8*)&Kl[(nf * 16 + lane16) * 136 + ks * 32 + quad * 8];
        s0 = MFMA(qf[0][ks], kf, s0);
        s1 = MFMA(qf[1][ks], kf, s1);
      }
#pragma unroll
      for (int r = 0; r < 4; ++r) {
        Pw[(quad * 4 + r) * 72 + nf * 16 + lane16] =
            f2bf(__builtin_amdgcn_exp2f(s0[r]));
        Pw[(16 + quad * 4 + r) * 72 + nf * 16 + lane16] =
            f2bf(__builtin_amdgcn_exp2f(s1[r]));
      }
    }
    __threadfence_block();  // order P ds_writes before cross-lane ds_reads

    // O += P V ; l += P * ones
#pragma unroll
    for (int ks = 0; ks < 2; ++ks) {
      const short8 pf0 = *(const short8*)&Pw[lane16 * 72 + ks * 32 + quad * 8];
      const short8 pf1 = *(const short8*)&Pw[(16 + lane16) * 72 + ks * 32 + quad * 8];
      Lacc[0] = MFMA(pf0, ones, Lacc[0]);
      Lacc[1] = MFMA(pf1, ones, Lacc[1]);
#pragma unroll
      for (int nf = 0; nf < 8; ++nf) {
        const short8 vf = *(const short8*)&Vl[(nf * 16 + lane16) * 72 + ks * 32 + quad * 8];
        O[0][nf] = MFMA(pf0, vf, O[0][nf]);
        O[1][nf] = MFMA(pf1, vf, O[1][nf]);
      }
    }
  }

  const int chunk = (b * 32 + qt) * NKC + kc;
  float* Op = Opart + (size_t)chunk * (128 * 128);
#pragma unroll
  for (int mt = 0; mt < 2; ++mt)
#pragma unroll
    for (int nf = 0; nf < 8; ++nf)
#pragma unroll
      for (int r = 0; r < 4; ++r)
        Op[(size_t)(wave * 32 + mt * 16 + quad * 4 + r) * 128 + nf * 16 + lane16] = O[mt][nf][r];
  if (lane16 == 0) {
    float* Mp = Ml + (size_t)chunk * 128 + wave * 32;
#pragma unroll
    for (int mt = 0; mt < 2; ++mt)
#pragma unroll
      for (int r = 0; r < 4; ++r)
        Mp[mt * 16 + quad * 4 + r] = Lacc[mt][r];
  }
}

// ---------------------------------------------------------------------------
// Kernel 2b: combine = plain sum of partials (no max bookkeeping), normalize.
// grid 512 (b=blk>>7, qg=blk&127 -> 32 q rows), block 256.
// ---------------------------------------------------------------------------
template<int NKC>
__global__ __launch_bounds__(256) void combine_kernel(
    const float* __restrict__ Opart, const float* __restrict__ Ml,
    unsigned short* __restrict__ ctx)
{
  const int tid = threadIdx.x;
  const int blk = blockIdx.x;
  const int b  = blk >> 7;
  const int qg = blk & 127;           // group of 32 q rows
  const int qt = qg >> 2;             // 128-q tile
  const int qin = (qg & 3) * 32 + (tid >> 3);  // row within tile
  const int c16 = (tid & 7) * 16;

  const int chunk0 = (b * 32 + qt) * NKC;
  float L = 0.f;
#pragma unroll
  for (int k = 0; k < NKC; ++k) L += Ml[(size_t)(chunk0 + k) * 128 + qin];

  float acc[16];
#pragma unroll
  for (int i = 0; i < 16; ++i) acc[i] = 0.f;
#pragma unroll
  for (int k = 0; k < NKC; ++k) {
    const float* Op = Opart + (size_t)(chunk0 + k) * 16384 + (size_t)qin * 128 + c16;
#pragma unroll
    for (int j = 0; j < 4; ++j) {
      const float4 v = *(const float4*)(Op + j * 4);
      acc[j * 4 + 0] += v.x;
      acc[j * 4 + 1] += v.y;
      acc[j * 4 + 2] += v.z;
      acc[j * 4 + 3] += v.w;
    }
  }
  const float inv = 1.f / L;
  unsigned short* Cs = ctx + ((size_t)b * HW + qg * 32 + (tid >> 3)) * CK + c16;
#pragma unroll
  for (int i = 0; i < 16; ++i) Cs[i] = f2bf(acc[i] * inv);
}

// ---------------------------------------------------------------------------
// Kernel 3: out = Wo @ ctx^T + bo. grid (64, 4), block 256.
// ---------------------------------------------------------------------------
__global__ __launch_bounds__(256) void outproj_kernel(
    const unsigned short* __restrict__ ctx, const float* __restrict__ wo,
    const float* __restrict__ bo, float* __restrict__ out)
{
  const int tid = threadIdx.x;
  const int pt = blockIdx.x;
  const int b  = blockIdx.y;
  const int wave = tid >> 6;
  const int lane = tid & 63;
  const int lane16 = lane & 15;
  const int quad = lane >> 4;

  floatx4 acc[4][4];
#pragma unroll
  for (int mt = 0; mt < 4; ++mt)
#pragma unroll
    for (int nf = 0; nf < 4; ++nf) acc[mt][nf] = (floatx4){0.f, 0.f, 0.f, 0.f};

#pragma unroll
  for (int ks = 0; ks < 4; ++ks) {
    short8 af[4];
#pragma unroll
    for (int mt = 0; mt < 4; ++mt) {
      const int o = wave * 64 + mt * 16 + lane16;
      const float* Wr = wo + (size_t)o * CK + ks * 32 + quad * 8;
      float t[8];
      *(float4*)(t) = *(const float4*)(Wr);
      *(float4*)(t + 4) = *(const float4*)(Wr + 4);
      af[mt] = pack8(t);
    }
#pragma unroll
    for (int nf = 0; nf < 4; ++nf) {
      const short8 bf = *(const short8*)(ctx + ((size_t)b * HW + pt * 64 + nf * 16 + lane16) * CK + ks * 32 + quad * 8);
#pragma unroll
      for (int mt = 0; mt < 4; ++mt) acc[mt][nf] = MFMA(af[mt], bf, acc[mt][nf]);
    }
  }

#pragma unroll
  for (int mt = 0; mt < 4; ++mt) {
#pragma unroll
    for (int r = 0; r < 4; ++r) {
      const int o = wave * 64 + mt * 16 + quad * 4 + r;
      const float bias = bo[o];
      float* dst = out + ((size_t)b * COUT + o) * HW + pt * 64;
#pragma unroll
      for (int nf = 0; nf < 4; ++nf)
        dst[nf * 16 + lane16] = acc[mt][nf][r] + bias;
    }
  }
}

extern "C" void kernel_launch(void* const* d_in, const int* in_sizes, int n_in,
                              void* d_out, int out_size, void* d_ws, size_t ws_size,
                              hipStream_t stream)
{
  (void)in_sizes; (void)n_in; (void)out_size;
  const float* x_enc = (const float*)d_in[0];
  const float* x_dec = (const float*)d_in[1];
  const float* wk    = (const float*)d_in[2];
  const float* bk    = (const float*)d_in[3];
  const float* gk    = (const float*)d_in[4];
  const float* betak = (const float*)d_in[5];
  const float* mk    = (const float*)d_in[6];
  const float* vk    = (const float*)d_in[7];
  const float* wq    = (const float*)d_in[8];
  const float* bq    = (const float*)d_in[9];
  const float* gq    = (const float*)d_in[10];
  const float* betaq = (const float*)d_in[11];
  const float* mq    = (const float*)d_in[12];
  const float* vq    = (const float*)d_in[13];
  const float* wv    = (const float*)d_in[14];
  const float* bv    = (const float*)d_in[15];
  const float* wo    = (const float*)d_in[16];
  const float* bo    = (const float*)d_in[17];
  float* out = (float*)d_out;

  const size_t qkv = (size_t)NB * HW * CK;  // elems per bf16 tensor
  unsigned short* Qb  = (unsigned short*)d_ws;
  unsigned short* Kb  = Qb + qkv;
  unsigned short* Vt  = Kb + qkv;
  unsigned short* ctx = Vt + qkv;
  float* Opart = (float*)(ctx + qkv);       // after 16 MB of bf16 tensors
  const size_t bf16_bytes = 4 * qkv * 2;

  proj_kernel<<<dim3(64, 4, 3), 256, 0, stream>>>(
      x_enc, x_dec, wq, bq, gq, betaq, mq, vq,
      wk, bk, gk, betak, mk, vk, wv, bv, Qb, Kb, Vt);

  auto need = [&](int nkc) {
    return bf16_bytes + (size_t)128 * nkc * (16384 + 128) * sizeof(float);
  };
  if (ws_size >= need(4)) {
    float* Ml = Opart + (size_t)128 * 4 * 16384;
    attn_kernel3<4><<<dim3(512), 256, 0, stream>>>(Qb, Kb, Vt, Opart, Ml);
    combine_kernel<4><<<dim3(512), 256, 0, stream>>>(Opart, Ml, ctx);
  } else if (ws_size >= need(2)) {
    float* Ml = Opart + (size_t)128 * 2 * 16384;
    attn_kernel3<2><<<dim3(256), 256, 0, stream>>>(Qb, Kb, Vt, Opart, Ml);
    combine_kernel<2><<<dim3(512), 256, 0, stream>>>(Opart, Ml, ctx);
  } else {
    float* Ml = Opart + (size_t)128 * 1 * 16384;
    attn_kernel3<1><<<dim3(128), 256, 0, stream>>>(Qb, Kb, Vt, Opart, Ml);
    combine_kernel<1><<<dim3(512), 256, 0, stream>>>(Opart, Ml, ctx);
  }

  outproj_kernel<<<dim3(64, 4), 256, 0, stream>>>(ctx, wo, bo, out);
}